// Round 9
// baseline (891.245 us; speedup 1.0000x reference)
//
#include <hip/hip_runtime.h>
#include <math.h>
#include <stdint.h>

typedef float f32x2 __attribute__((ext_vector_type(2)));
typedef int   i32x2 __attribute__((ext_vector_type(2)));

namespace {
constexpr float kDT  = 0.01f;   // DT / SUBSTEP, SUBSTEP == 1
constexpr int   kIter = 10;
constexpr float kH   = -2.0f;
constexpr float kEps = 1e-5f;
constexpr int   kB = 8;
constexpr int   kN = 50000;
constexpr int   kE = 200000;
constexpr int   kBN = kB * kN;
constexpr int   kNB = (kN + 255) / 256;   // 196 blocks for per-vertex kernels
constexpr int   kBins = 64;               // degree bins (clamped)
constexpr int   kM = kBins * kNB;         // (bin, block) table size
constexpr int   kVCH = (kN + 63) / 64;    // 782 chunks of 64 sorted vertices
constexpr int   kSweepBlocks = ((kVCH + 3) / 4) * 8;
constexpr int   kHalfP = kN * 4;          // float4 entries per half P plane
constexpr int   kHalfS = 2 * kE * 4;      // (slot,b4) entries per half
}

// ---------------- CSR build ----------------

__global__ void count_kernel(const int2* __restrict__ Cdist, int* __restrict__ deg) {
    int e = blockIdx.x * blockDim.x + threadIdx.x;
    if (e >= kE) return;
    int2 c = Cdist[e];
    atomicAdd(&deg[c.x], 1);
    atomicAdd(&deg[c.y], 1);
}

__global__ void partial_sum_kernel(const int* __restrict__ in, int* __restrict__ blkSum) {
    __shared__ int s[256];
    int i = blockIdx.x * 256 + threadIdx.x;
    s[threadIdx.x] = (i < kN) ? in[i] : 0;
    __syncthreads();
    for (int off = 128; off > 0; off >>= 1) {
        if (threadIdx.x < off) s[threadIdx.x] += s[threadIdx.x + off];
        __syncthreads();
    }
    if (threadIdx.x == 0) blkSum[blockIdx.x] = s[0];
}

__global__ void scan_sums_kernel(const int* __restrict__ blkSum, int* __restrict__ blkOff) {
    __shared__ int s[kNB];
    int tid = threadIdx.x;                 // 256 threads >= kNB
    if (tid < kNB) s[tid] = blkSum[tid];
    __syncthreads();
    if (tid == 0) {
        int acc = 0;
        for (int i = 0; i < kNB; ++i) { int v = s[i]; s[i] = acc; acc += v; }
    }
    __syncthreads();
    if (tid < kNB) blkOff[tid] = s[tid];
}

__global__ void scatter_scan_kernel(const int* __restrict__ in,
                                    const int* __restrict__ blkOff,
                                    int* __restrict__ out) {
    __shared__ int s[256];
    int tid = threadIdx.x;
    int i = blockIdx.x * 256 + tid;
    int c = (i < kN) ? in[i] : 0;
    s[tid] = c;
    __syncthreads();
    for (int off = 1; off < 256; off <<= 1) {      // inclusive Hillis-Steele
        int v = (tid >= off) ? s[tid - off] : 0;
        __syncthreads();
        s[tid] += v;
        __syncthreads();
    }
    int incl = s[tid];
    int excl = incl - c;
    if (i < kN) out[i] = blkOff[blockIdx.x] + excl;
    if (i == kN - 1) out[kN] = blkOff[blockIdx.x] + incl;   // == 2E
}

// inc id = 2*e + side. Atomic fill order only permutes slot order within a
// vertex; summation-order FP wiggle is far below tolerance (validated R1-R8).
__global__ void fill_kernel(const int2* __restrict__ Cdist, int* __restrict__ cursor,
                            int* __restrict__ inc) {
    int e = blockIdx.x * blockDim.x + threadIdx.x;
    if (e >= kE) return;
    int2 c = Cdist[e];
    int p0 = atomicAdd(&cursor[c.x], 1);
    inc[p0] = 2 * e;
    int p1 = atomicAdd(&cursor[c.y], 1);
    inc[p1] = 2 * e + 1;
}

// ---------------- degree-sorted order (contention-free counting sort) -------

__device__ __forceinline__ int clamp_deg(int d) {
    return d > kBins - 1 ? kBins - 1 : d;
}

__global__ void blk_hist_kernel(const int* __restrict__ deg, int* __restrict__ blkHist) {
    __shared__ int lh[kBins];
    int tid = threadIdx.x;
    if (tid < kBins) lh[tid] = 0;
    __syncthreads();
    int v = blockIdx.x * 256 + tid;
    if (v < kN) atomicAdd(&lh[clamp_deg(deg[v])], 1);   // LDS atomic: cheap
    __syncthreads();
    if (tid < kBins) blkHist[(kBins - 1 - tid) * kNB + blockIdx.x] = lh[tid];
}

__global__ void sort_scan_kernel(const int* __restrict__ in, int* __restrict__ out) {
    __shared__ int part[1024];
    int tid = threadIdx.x;
    const int CH = (kM + 1023) / 1024;
    int lo = tid * CH;
    int hi = lo + CH; if (hi > kM) hi = kM;
    int s = 0;
    for (int m = lo; m < hi; ++m) s += in[m];
    part[tid] = s;
    __syncthreads();
    for (int off = 1; off < 1024; off <<= 1) {
        int v = (tid >= off) ? part[tid - off] : 0;
        __syncthreads();
        part[tid] += v;
        __syncthreads();
    }
    int base = tid ? part[tid - 1] : 0;
    for (int m = lo; m < hi; ++m) { out[m] = base; base += in[m]; }
}

__global__ void order_scatter_kernel(const int* __restrict__ deg,
                                     const int* __restrict__ scanned,
                                     int* __restrict__ order) {
    __shared__ int lh[kBins];
    int tid = threadIdx.x;
    if (tid < kBins) lh[tid] = 0;
    __syncthreads();
    int v = blockIdx.x * 256 + tid;
    if (v < kN) {
        int d = clamp_deg(deg[v]);
        int lr = atomicAdd(&lh[d], 1);                  // LDS atomic: cheap
        int pos = scanned[(kBins - 1 - d) * kNB + blockIdx.x] + lr;
        order[pos] = v;
    }
}

// rank + sorted-degree array (for the sorted slot re-layout scan)
__global__ void rank_kernel(const int* __restrict__ order, const int* __restrict__ start,
                            int* __restrict__ rank, int* __restrict__ degS) {
    int g = blockIdx.x * blockDim.x + threadIdx.x;
    if (g >= kN) return;
    int v = order[g];
    rank[v] = g;
    degS[g] = start[v + 1] - start[v];
}

// ---------------- predict (original order, coalesced) + permute to sorted ---

__global__ void predict_kernel(const float* __restrict__ V,
                               const float* __restrict__ Vvel,
                               const float* __restrict__ Vw,
                               const float* __restrict__ Vcomp,
                               const float* __restrict__ Vmass,
                               const float* __restrict__ Vforce,
                               float4* __restrict__ Ptmp,
                               float2* __restrict__ WCtmp) {
    int v = blockIdx.x * blockDim.x + threadIdx.x;
    if (v >= kN) return;
#pragma unroll
    for (int b = 0; b < kB; ++b) {
        int idx = b * kN + v;
        int k = idx * 3;
        float m = Vmass[idx];
        float4 r;
        float vpx = Vvel[k + 0] + (kDT * Vforce[k + 0]) / m;   // (dt*F)/m, reference order
        float vpy = Vvel[k + 1] + (kDT * Vforce[k + 1]) / m;
        float vpz = Vvel[k + 2] + (kDT * Vforce[k + 2]) / m;
        float w = Vw[idx];
        r.x = V[k + 0] + kDT * vpx;
        r.y = V[k + 1] + kDT * vpy;
        r.z = V[k + 2] + kDT * vpz;
        r.w = w;
        Ptmp[v * 8 + b] = r;
        WCtmp[v * 8 + b] = make_float2(w, Vcomp[idx]);
    }
}

__global__ void permute_kernel(const int* __restrict__ order,
                               const float4* __restrict__ Ptmp,
                               const float2* __restrict__ WCtmp,
                               float4* __restrict__ Ps,       // [2][kHalfP]
                               float2* __restrict__ WCs) {
    int tid = blockIdx.x * blockDim.x + threadIdx.x;
    if (tid >= 8 * kN) return;
    int g = tid >> 3, b = tid & 7;
    int v = order[g];
    int h = b >> 2, b4 = b & 3;
    Ps[(size_t)h * kHalfP + g * 4 + b4] = Ptmp[v * 8 + b];
    WCs[g * 8 + b] = WCtmp[v * 8 + b];
}

// ---------------- sorted slot arrays: SSI + per-(slot,batch) constants ------
// A and S are symmetric (commutative adds) -> both slot copies of an edge get
// bitwise-identical constants, so duplicated L stays bitwise in sync.
__global__ void slots_build_kernel(const int* __restrict__ order,
                                   const int* __restrict__ rank,
                                   const int* __restrict__ start,
                                   const int* __restrict__ nstart,
                                   const int* __restrict__ inc,
                                   const int2* __restrict__ Cdist,
                                   const float* __restrict__ Cinit,
                                   const float2* __restrict__ WCs,
                                   i32x2* __restrict__ SSI,
                                   f32x2* __restrict__ AS) {   // [2][kHalfS]
    int tid = blockIdx.x * blockDim.x + threadIdx.x;
    if (tid >= 8 * kN) return;
    int g = tid >> 3, b = tid & 7;
    int v = order[g];
    int os = start[v];
    int d = start[v + 1] - os;
    int ns = nstart[g];
    int h = b >> 2, b4 = b & 3;
    float2 wo = WCs[g * 8 + b];
    f32x2* Ah = AS + (size_t)h * kHalfS;
    for (int t = 0; t < d; ++t) {
        int ic = inc[os + t];
        int e = ic >> 1;
        int2 c = Cdist[e];
        int other = (ic & 1) ? c.x : c.y;
        int og = rank[other];
        float2 wj = WCs[og * 8 + b];
        float A = (wo.y + wj.y) * 0.5f;
        float S = wo.x + wj.x;
        if (S == 0.0f) S = INFINITY;
        int nk = ns + t;
        f32x2 a; a.x = A; a.y = 1.0f / (S + A);
        Ah[(size_t)nk * 4 + b4] = a;
        if (b == 0) { i32x2 s2; s2.x = og; s2.y = __float_as_int(Cinit[e]); SSI[nk] = s2; }
    }
}

// ---------------- fused Jacobi sweep ----------------
// Block -> (half h via bid%8: {0..3}=h0 on XCDs0-3, {4..7}=h1), chunk of 64
// sorted vertices. Thread = (g, b4). Random access = only the neighbor gather,
// into a 3.2MB half plane (< 4MB per-XCD L2). SSI/AS/L are pure sequential
// streams (sorted slot layout), loaded/stored nontemporally to spare L2.
__global__ __launch_bounds__(256)
void sweep_kernel(const float4* __restrict__ Psrc,
                  float4* __restrict__ Pdst,
                  float* __restrict__ L,            // [2][kHalfS], in-place
                  const f32x2* __restrict__ AS,
                  const i32x2* __restrict__ SSI,
                  const int* __restrict__ nstart) {
    int bid = blockIdx.x;
    int x8 = bid & 7;
    int h = x8 >> 2;
    int chunk = (bid >> 3) * 4 + (x8 & 3);
    if (chunk >= kVCH) return;
    int g = chunk * 64 + (threadIdx.x >> 2);
    int b4 = threadIdx.x & 3;
    if (g >= kN) return;

    const float4* Ps = Psrc + (size_t)h * kHalfP;
    float4*       Pd = Pdst + (size_t)h * kHalfP;
    float*        Lh = L    + (size_t)h * kHalfS;
    const f32x2*  Ah = AS   + (size_t)h * kHalfS;

    float4 own = Ps[g * 4 + b4];
    int s0 = nstart[g], s1 = nstart[g + 1];
    float ax = 0.f, ay = 0.f, az = 0.f;
    for (int k = s0; k < s1; ++k) {
        i32x2 ss = __builtin_nontemporal_load(&SSI[k]);        // broadcast 4 lanes
        float4 oth = Ps[(size_t)ss.x * 4 + b4];                // L2-resident plane
        f32x2 a = __builtin_nontemporal_load(&Ah[(size_t)k * 4 + b4]);
        float Lold = __builtin_nontemporal_load(&Lh[(size_t)k * 4 + b4]);
        float dx = own.x - oth.x;
        float dy = own.y - oth.y;
        float dz = own.z - oth.z;
        float D = sqrtf(dx * dx + dy * dy + dz * dz);
        float C = D - __int_as_float(ss.y);
        float Ld = (-C - a.x * Lold) * a.y;
        __builtin_nontemporal_store(Lold + Ld, &Lh[(size_t)k * 4 + b4]);
        float rD = 1.0f / D;
        ax += Ld * (dx * rD);
        ay += Ld * (dy * rD);
        az += Ld * (dz * rD);
    }
    Pd[g * 4 + b4] = make_float4(own.x + own.w * ax,
                                 own.y + own.w * ay,
                                 own.z + own.w * az, own.w);
}

// ---------------- finalize: un-sort + plane collision + velocity ------------
// Thread per original vertex v: sorted-P reads are random but full-64B-line
// granular; all output writes coalesced.
__global__ void finalize_kernel(const float4* __restrict__ Pfin,   // [2][kHalfP]
                                const int* __restrict__ rank,
                                const float* __restrict__ V,
                                float* __restrict__ outV,
                                float* __restrict__ outVel) {
    int v = blockIdx.x * blockDim.x + threadIdx.x;
    if (v >= kN) return;
    int g = rank[v];
#pragma unroll
    for (int b = 0; b < kB; ++b) {
        int h = b >> 2, b4 = b & 3;
        float4 p = Pfin[(size_t)h * kHalfP + g * 4 + b4];
        float px = p.x, py = p.y, pz = p.z;
        int k3 = (b * kN + v) * 3;
        float vx = V[k3], vy = V[k3 + 1], vz0 = V[k3 + 2];

        bool col = (pz < kH) && (vz0 > kH);
        float h_prev = vz0 - kH;
        float h_after = kH - pz;
        float denom = col ? (h_prev + h_after) : 1.0f;
        float tt = h_prev / denom;

        float x  = col ? (vx + tt * (px - vx)) : px;
        float y  = col ? (vy + tt * (py - vy)) : py;
        float z1 = col ? (kH + kEps) : pz;

        bool vio = (z1 < kH) && (vz0 < kH);
        float z2 = vio ? (kH + kEps) : z1;

        float velx = (x  - vx ) / kDT;
        float vely = (y  - vy ) / kDT;
        float velz = (z2 - vz0) / kDT;
        velz = col ? -velz : velz;
        velz = vio ? 0.0f : velz;

        outV[k3] = x;  outV[k3 + 1] = y;  outV[k3 + 2] = z2;
        outVel[k3] = velx; outVel[k3 + 1] = vely; outVel[k3 + 2] = velz;
    }
}

// ---------------- launch ----------------

extern "C" void kernel_launch(void* const* d_in, const int* in_sizes, int n_in,
                              void* d_out, int out_size, void* d_ws, size_t ws_size,
                              hipStream_t stream) {
    const float* V      = (const float*)d_in[0];
    const float* Vvel   = (const float*)d_in[1];
    const float* Vw     = (const float*)d_in[2];
    const float* Vcomp  = (const float*)d_in[3];
    const float* Vmass  = (const float*)d_in[4];
    const float* Vforce = (const float*)d_in[5];
    const float* Cinit  = (const float*)d_in[6];
    const int2*  Cdist  = (const int2*)d_in[7];

    char* p = (char*)d_ws;
    auto alloc = [&](size_t bytes) -> void* {
        p = (char*)(((uintptr_t)p + 255) & ~(uintptr_t)255);
        void* r = (void*)p;
        p += bytes;
        return r;
    };

    float4* Ptmp   = (float4*)alloc((size_t)kN * 8 * sizeof(float4));       // 6.4 MB
    float4* PA     = (float4*)alloc((size_t)2 * kHalfP * sizeof(float4));   // 6.4 MB
    float4* PB     = (float4*)alloc((size_t)2 * kHalfP * sizeof(float4));   // 6.4 MB
    float*  L      = (float*)alloc((size_t)2 * kHalfS * sizeof(float));     // 12.8 MB
    f32x2*  AS     = (f32x2*)alloc((size_t)2 * kHalfS * sizeof(f32x2));     // 25.6 MB
    i32x2*  SSI    = (i32x2*)alloc((size_t)2 * kE * sizeof(i32x2));         // 3.2 MB
    float2* WCtmp  = (float2*)alloc((size_t)kN * 8 * sizeof(float2));       // 3.2 MB
    float2* WCs    = (float2*)alloc((size_t)kN * 8 * sizeof(float2));       // 3.2 MB
    int*    start  = (int*)alloc((size_t)(kN + 1) * sizeof(int));
    int*    nstart = (int*)alloc((size_t)(kN + 1) * sizeof(int));
    int*    deg    = (int*)alloc((size_t)kN * sizeof(int));
    int*    degS   = (int*)alloc((size_t)kN * sizeof(int));
    int*    cursor = (int*)alloc((size_t)kN * sizeof(int));
    int*    order  = (int*)alloc((size_t)kN * sizeof(int));
    int*    rank   = (int*)alloc((size_t)kN * sizeof(int));
    int*    inc    = (int*)alloc((size_t)2 * kE * sizeof(int));
    int*    blkSum = (int*)alloc((size_t)kNB * sizeof(int));
    int*    blkOff = (int*)alloc((size_t)kNB * sizeof(int));
    int*    blkHist= (int*)alloc((size_t)kM * sizeof(int));
    int*    scanned= (int*)alloc((size_t)kM * sizeof(int));

    const int TB = 256;
    dim3 blk(TB);
    dim3 gE((kE + TB - 1) / TB);
    dim3 gN(kNB);
    dim3 g8N((8 * kN + TB - 1) / TB);

    // CSR build
    hipMemsetAsync(deg, 0, kN * sizeof(int), stream);
    count_kernel<<<gE, blk, 0, stream>>>(Cdist, deg);
    partial_sum_kernel<<<gN, blk, 0, stream>>>(deg, blkSum);
    scan_sums_kernel<<<dim3(1), blk, 0, stream>>>(blkSum, blkOff);
    scatter_scan_kernel<<<gN, blk, 0, stream>>>(deg, blkOff, start);
    hipMemcpyAsync(cursor, start, kN * sizeof(int), hipMemcpyDeviceToDevice, stream);
    fill_kernel<<<gE, blk, 0, stream>>>(Cdist, cursor, inc);

    // degree-sorted order, rank, sorted-degree scan -> nstart
    blk_hist_kernel<<<gN, blk, 0, stream>>>(deg, blkHist);
    sort_scan_kernel<<<dim3(1), dim3(1024), 0, stream>>>(blkHist, scanned);
    order_scatter_kernel<<<gN, blk, 0, stream>>>(deg, scanned, order);
    rank_kernel<<<gN, blk, 0, stream>>>(order, start, rank, degS);
    partial_sum_kernel<<<gN, blk, 0, stream>>>(degS, blkSum);
    scan_sums_kernel<<<dim3(1), blk, 0, stream>>>(blkSum, blkOff);
    scatter_scan_kernel<<<gN, blk, 0, stream>>>(degS, blkOff, nstart);

    // predict (coalesced) -> permute to sorted half planes -> slot arrays
    predict_kernel<<<gN, blk, 0, stream>>>(V, Vvel, Vw, Vcomp, Vmass, Vforce, Ptmp, WCtmp);
    permute_kernel<<<g8N, blk, 0, stream>>>(order, Ptmp, WCtmp, PA, WCs);
    slots_build_kernel<<<g8N, blk, 0, stream>>>(order, rank, start, nstart, inc,
                                                Cdist, Cinit, WCs, SSI, AS);
    hipMemsetAsync(L, 0, (size_t)2 * kHalfS * sizeof(float), stream);

    dim3 gS(kSweepBlocks);
    for (int it = 0; it < kIter; ++it) {
        float4* src = (it & 1) ? PB : PA;
        float4* dst = (it & 1) ? PA : PB;
        sweep_kernel<<<gS, blk, 0, stream>>>(src, dst, L, AS, SSI, nstart);
    }
    // 10 sweeps: final positions in PA. Un-sort + collision + velocity.
    float* outV   = (float*)d_out;
    float* outVel = outV + (size_t)kBN * 3;
    finalize_kernel<<<gN, blk, 0, stream>>>(PA, rank, V, outV, outVel);
}

// Round 10
// 490.378 us; speedup vs baseline: 1.8175x; 1.8175x over previous
//
#include <hip/hip_runtime.h>
#include <math.h>
#include <stdint.h>

typedef int i32x2 __attribute__((ext_vector_type(2)));

namespace {
constexpr float kDT  = 0.01f;   // DT / SUBSTEP, SUBSTEP == 1
constexpr int   kIter = 10;
constexpr float kH   = -2.0f;
constexpr float kEps = 1e-5f;
constexpr int   kB = 8;
constexpr int   kN = 50000;
constexpr int   kE = 200000;
constexpr int   kBN = kB * kN;
constexpr int   kNB = (kN + 255) / 256;   // 196 blocks for per-vertex kernels
constexpr int   kBins = 64;               // degree bins (clamped)
constexpr int   kM = kBins * kNB;         // (bin, block) table size
constexpr int   kVCH = (kN + 63) / 64;    // 782 chunks of 64 sorted vertices
constexpr int   kSweepBlocks = ((kVCH + 3) / 4) * 8;
constexpr int   kHalfP = kN * 4;          // float4 entries per half P plane
constexpr int   kHalfS = 2 * kE * 4;      // (slot,b4) entries per half
}

// ---------------- CSR build ----------------

__global__ void count_kernel(const int2* __restrict__ Cdist, int* __restrict__ deg) {
    int e = blockIdx.x * blockDim.x + threadIdx.x;
    if (e >= kE) return;
    int2 c = Cdist[e];
    atomicAdd(&deg[c.x], 1);
    atomicAdd(&deg[c.y], 1);
}

__global__ void partial_sum_kernel(const int* __restrict__ in, int* __restrict__ blkSum) {
    __shared__ int s[256];
    int i = blockIdx.x * 256 + threadIdx.x;
    s[threadIdx.x] = (i < kN) ? in[i] : 0;
    __syncthreads();
    for (int off = 128; off > 0; off >>= 1) {
        if (threadIdx.x < off) s[threadIdx.x] += s[threadIdx.x + off];
        __syncthreads();
    }
    if (threadIdx.x == 0) blkSum[blockIdx.x] = s[0];
}

__global__ void scan_sums_kernel(const int* __restrict__ blkSum, int* __restrict__ blkOff) {
    __shared__ int s[kNB];
    int tid = threadIdx.x;                 // 256 threads >= kNB
    if (tid < kNB) s[tid] = blkSum[tid];
    __syncthreads();
    if (tid == 0) {
        int acc = 0;
        for (int i = 0; i < kNB; ++i) { int v = s[i]; s[i] = acc; acc += v; }
    }
    __syncthreads();
    if (tid < kNB) blkOff[tid] = s[tid];
}

__global__ void scatter_scan_kernel(const int* __restrict__ in,
                                    const int* __restrict__ blkOff,
                                    int* __restrict__ out) {
    __shared__ int s[256];
    int tid = threadIdx.x;
    int i = blockIdx.x * 256 + tid;
    int c = (i < kN) ? in[i] : 0;
    s[tid] = c;
    __syncthreads();
    for (int off = 1; off < 256; off <<= 1) {      // inclusive Hillis-Steele
        int v = (tid >= off) ? s[tid - off] : 0;
        __syncthreads();
        s[tid] += v;
        __syncthreads();
    }
    int incl = s[tid];
    int excl = incl - c;
    if (i < kN) out[i] = blkOff[blockIdx.x] + excl;
    if (i == kN - 1) out[kN] = blkOff[blockIdx.x] + incl;   // == 2E
}

// inc id = 2*e + side. Atomic fill order only permutes slot order within a
// vertex; summation-order FP wiggle is far below tolerance (validated R1-R9).
__global__ void fill_kernel(const int2* __restrict__ Cdist, int* __restrict__ cursor,
                            int* __restrict__ inc) {
    int e = blockIdx.x * blockDim.x + threadIdx.x;
    if (e >= kE) return;
    int2 c = Cdist[e];
    int p0 = atomicAdd(&cursor[c.x], 1);
    inc[p0] = 2 * e;
    int p1 = atomicAdd(&cursor[c.y], 1);
    inc[p1] = 2 * e + 1;
}

// ---------------- degree-sorted order (contention-free counting sort) -------

__device__ __forceinline__ int clamp_deg(int d) {
    return d > kBins - 1 ? kBins - 1 : d;
}

__global__ void blk_hist_kernel(const int* __restrict__ deg, int* __restrict__ blkHist) {
    __shared__ int lh[kBins];
    int tid = threadIdx.x;
    if (tid < kBins) lh[tid] = 0;
    __syncthreads();
    int v = blockIdx.x * 256 + tid;
    if (v < kN) atomicAdd(&lh[clamp_deg(deg[v])], 1);   // LDS atomic: cheap
    __syncthreads();
    if (tid < kBins) blkHist[(kBins - 1 - tid) * kNB + blockIdx.x] = lh[tid];
}

__global__ void sort_scan_kernel(const int* __restrict__ in, int* __restrict__ out) {
    __shared__ int part[1024];
    int tid = threadIdx.x;
    const int CH = (kM + 1023) / 1024;
    int lo = tid * CH;
    int hi = lo + CH; if (hi > kM) hi = kM;
    int s = 0;
    for (int m = lo; m < hi; ++m) s += in[m];
    part[tid] = s;
    __syncthreads();
    for (int off = 1; off < 1024; off <<= 1) {
        int v = (tid >= off) ? part[tid - off] : 0;
        __syncthreads();
        part[tid] += v;
        __syncthreads();
    }
    int base = tid ? part[tid - 1] : 0;
    for (int m = lo; m < hi; ++m) { out[m] = base; base += in[m]; }
}

__global__ void order_scatter_kernel(const int* __restrict__ deg,
                                     const int* __restrict__ scanned,
                                     int* __restrict__ order) {
    __shared__ int lh[kBins];
    int tid = threadIdx.x;
    if (tid < kBins) lh[tid] = 0;
    __syncthreads();
    int v = blockIdx.x * 256 + tid;
    if (v < kN) {
        int d = clamp_deg(deg[v]);
        int lr = atomicAdd(&lh[d], 1);                  // LDS atomic: cheap
        int pos = scanned[(kBins - 1 - d) * kNB + blockIdx.x] + lr;
        order[pos] = v;
    }
}

// rank + sorted-degree array (for the sorted slot re-layout scan)
__global__ void rank_kernel(const int* __restrict__ order, const int* __restrict__ start,
                            int* __restrict__ rank, int* __restrict__ degS) {
    int g = blockIdx.x * blockDim.x + threadIdx.x;
    if (g >= kN) return;
    int v = order[g];
    rank[v] = g;
    degS[g] = start[v + 1] - start[v];
}

// ---------------- predict (original order, coalesced) + permute to sorted ---

__global__ void predict_kernel(const float* __restrict__ V,
                               const float* __restrict__ Vvel,
                               const float* __restrict__ Vw,
                               const float* __restrict__ Vcomp,
                               const float* __restrict__ Vmass,
                               const float* __restrict__ Vforce,
                               float4* __restrict__ Ptmp,
                               float2* __restrict__ WCtmp) {
    int v = blockIdx.x * blockDim.x + threadIdx.x;
    if (v >= kN) return;
#pragma unroll
    for (int b = 0; b < kB; ++b) {
        int idx = b * kN + v;
        int k = idx * 3;
        float m = Vmass[idx];
        float4 r;
        float vpx = Vvel[k + 0] + (kDT * Vforce[k + 0]) / m;   // (dt*F)/m, reference order
        float vpy = Vvel[k + 1] + (kDT * Vforce[k + 1]) / m;
        float vpz = Vvel[k + 2] + (kDT * Vforce[k + 2]) / m;
        float w = Vw[idx];
        r.x = V[k + 0] + kDT * vpx;
        r.y = V[k + 1] + kDT * vpy;
        r.z = V[k + 2] + kDT * vpz;
        r.w = w;
        Ptmp[v * 8 + b] = r;
        WCtmp[v * 8 + b] = make_float2(w, Vcomp[idx]);
    }
}

__global__ void permute_kernel(const int* __restrict__ order,
                               const float4* __restrict__ Ptmp,
                               const float2* __restrict__ WCtmp,
                               float4* __restrict__ Ps,       // [2][kHalfP]
                               float2* __restrict__ WCs) {
    int tid = blockIdx.x * blockDim.x + threadIdx.x;
    if (tid >= 8 * kN) return;
    int g = tid >> 3, b = tid & 7;
    int v = order[g];
    int h = b >> 2, b4 = b & 3;
    Ps[(size_t)h * kHalfP + g * 4 + b4] = Ptmp[v * 8 + b];
    WCs[g * 8 + b] = WCtmp[v * 8 + b];
}

// ---------------- sorted slot arrays: SSI + per-(slot,batch) A --------------
// A is symmetric (commutative add) -> both slot copies of an edge get
// bitwise-identical constants, so duplicated L stays bitwise in sync.
__global__ void slots_build_kernel(const int* __restrict__ order,
                                   const int* __restrict__ rank,
                                   const int* __restrict__ start,
                                   const int* __restrict__ nstart,
                                   const int* __restrict__ inc,
                                   const int2* __restrict__ Cdist,
                                   const float* __restrict__ Cinit,
                                   const float2* __restrict__ WCs,
                                   i32x2* __restrict__ SSI,
                                   float* __restrict__ Aarr) {  // [2][kHalfS]
    int tid = blockIdx.x * blockDim.x + threadIdx.x;
    if (tid >= 8 * kN) return;
    int g = tid >> 3, b = tid & 7;
    int v = order[g];
    int os = start[v];
    int d = start[v + 1] - os;
    int ns = nstart[g];
    int h = b >> 2, b4 = b & 3;
    float2 wo = WCs[g * 8 + b];
    float* Ah = Aarr + (size_t)h * kHalfS;
    for (int t = 0; t < d; ++t) {
        int ic = inc[os + t];
        int e = ic >> 1;
        int2 c = Cdist[e];
        int other = (ic & 1) ? c.x : c.y;
        int og = rank[other];
        float2 wj = WCs[og * 8 + b];
        float A = (wo.y + wj.y) * 0.5f;
        int nk = ns + t;
        Ah[(size_t)nk * 4 + b4] = A;
        if (b == 0) { i32x2 s2; s2.x = og; s2.y = __float_as_int(Cinit[e]); SSI[nk] = s2; }
    }
}

// ---------------- fused Jacobi sweep ----------------
// Block -> (half h via bid%8, chunk of 64 sorted vertices). Thread = (g, b4).
// Streams (SSI/A/L/P own) are sequential in sorted slot order; the only random
// access is the neighbor gather (64B line fully consumed by the 4-lane group).
// rSA = 1/(S+A) recomputed here: S = own.w + oth.w, IEEE divide — bitwise
// equal to the precomputed value it replaces. S==0 -> Ld=0 matches inf.
// 2-deep SSI pipeline breaks the SSI->gather address dependence across iters.
__global__ __launch_bounds__(256)
void sweep_kernel(const float4* __restrict__ Psrc,
                  float4* __restrict__ Pdst,
                  float* __restrict__ L,            // [2][kHalfS], in-place
                  const float* __restrict__ Aarr,
                  const i32x2* __restrict__ SSI,
                  const int* __restrict__ nstart) {
    int bid = blockIdx.x;
    int x8 = bid & 7;
    int h = x8 >> 2;
    int chunk = (bid >> 3) * 4 + (x8 & 3);
    if (chunk >= kVCH) return;
    int g = chunk * 64 + (threadIdx.x >> 2);
    int b4 = threadIdx.x & 3;
    if (g >= kN) return;

    const float4* Ps = Psrc + (size_t)h * kHalfP;
    float4*       Pd = Pdst + (size_t)h * kHalfP;
    float*        Lh = L    + (size_t)h * kHalfS;
    const float*  Ah = Aarr + (size_t)h * kHalfS;

    float4 own = Ps[g * 4 + b4];
    int s0 = nstart[g], s1 = nstart[g + 1];
    float ax = 0.f, ay = 0.f, az = 0.f;
    if (s0 < s1) {
        i32x2 ss = SSI[s0];
        for (int k = s0; k < s1; ++k) {
            i32x2 ssn = (k + 1 < s1) ? SSI[k + 1] : ss;    // prefetch next
            float4 oth = Ps[(size_t)ss.x * 4 + b4];        // random 64B line
            float A = Ah[(size_t)k * 4 + b4];
            float Lold = Lh[(size_t)k * 4 + b4];
            float dx = own.x - oth.x;
            float dy = own.y - oth.y;
            float dz = own.z - oth.z;
            float D = sqrtf(dx * dx + dy * dy + dz * dz);
            float C = D - __int_as_float(ss.y);
            float S = own.w + oth.w;
            float rSA = (S == 0.0f) ? 0.0f : 1.0f / (S + A);
            float Ld = (-C - A * Lold) * rSA;
            Lh[(size_t)k * 4 + b4] = Lold + Ld;
            float rD = 1.0f / D;
            ax += Ld * (dx * rD);
            ay += Ld * (dy * rD);
            az += Ld * (dz * rD);
            ss = ssn;
        }
    }
    Pd[g * 4 + b4] = make_float4(own.x + own.w * ax,
                                 own.y + own.w * ay,
                                 own.z + own.w * az, own.w);
}

// ---------------- finalize: un-sort + plane collision + velocity ------------

__global__ void finalize_kernel(const float4* __restrict__ Pfin,   // [2][kHalfP]
                                const int* __restrict__ rank,
                                const float* __restrict__ V,
                                float* __restrict__ outV,
                                float* __restrict__ outVel) {
    int v = blockIdx.x * blockDim.x + threadIdx.x;
    if (v >= kN) return;
    int g = rank[v];
#pragma unroll
    for (int b = 0; b < kB; ++b) {
        int h = b >> 2, b4 = b & 3;
        float4 p = Pfin[(size_t)h * kHalfP + g * 4 + b4];
        float px = p.x, py = p.y, pz = p.z;
        int k3 = (b * kN + v) * 3;
        float vx = V[k3], vy = V[k3 + 1], vz0 = V[k3 + 2];

        bool col = (pz < kH) && (vz0 > kH);
        float h_prev = vz0 - kH;
        float h_after = kH - pz;
        float denom = col ? (h_prev + h_after) : 1.0f;
        float tt = h_prev / denom;

        float x  = col ? (vx + tt * (px - vx)) : px;
        float y  = col ? (vy + tt * (py - vy)) : py;
        float z1 = col ? (kH + kEps) : pz;

        bool vio = (z1 < kH) && (vz0 < kH);
        float z2 = vio ? (kH + kEps) : z1;

        float velx = (x  - vx ) / kDT;
        float vely = (y  - vy ) / kDT;
        float velz = (z2 - vz0) / kDT;
        velz = col ? -velz : velz;
        velz = vio ? 0.0f : velz;

        outV[k3] = x;  outV[k3 + 1] = y;  outV[k3 + 2] = z2;
        outVel[k3] = velx; outVel[k3 + 1] = vely; outVel[k3 + 2] = velz;
    }
}

// ---------------- launch ----------------

extern "C" void kernel_launch(void* const* d_in, const int* in_sizes, int n_in,
                              void* d_out, int out_size, void* d_ws, size_t ws_size,
                              hipStream_t stream) {
    const float* V      = (const float*)d_in[0];
    const float* Vvel   = (const float*)d_in[1];
    const float* Vw     = (const float*)d_in[2];
    const float* Vcomp  = (const float*)d_in[3];
    const float* Vmass  = (const float*)d_in[4];
    const float* Vforce = (const float*)d_in[5];
    const float* Cinit  = (const float*)d_in[6];
    const int2*  Cdist  = (const int2*)d_in[7];

    char* p = (char*)d_ws;
    auto alloc = [&](size_t bytes) -> void* {
        p = (char*)(((uintptr_t)p + 255) & ~(uintptr_t)255);
        void* r = (void*)p;
        p += bytes;
        return r;
    };

    float4* Ptmp   = (float4*)alloc((size_t)kN * 8 * sizeof(float4));       // 6.4 MB
    float4* PA     = (float4*)alloc((size_t)2 * kHalfP * sizeof(float4));   // 6.4 MB
    float4* PB     = (float4*)alloc((size_t)2 * kHalfP * sizeof(float4));   // 6.4 MB
    float*  L      = (float*)alloc((size_t)2 * kHalfS * sizeof(float));     // 12.8 MB
    float*  Aarr   = (float*)alloc((size_t)2 * kHalfS * sizeof(float));     // 12.8 MB
    i32x2*  SSI    = (i32x2*)alloc((size_t)2 * kE * sizeof(i32x2));         // 3.2 MB
    float2* WCtmp  = (float2*)alloc((size_t)kN * 8 * sizeof(float2));       // 3.2 MB
    float2* WCs    = (float2*)alloc((size_t)kN * 8 * sizeof(float2));       // 3.2 MB
    int*    start  = (int*)alloc((size_t)(kN + 1) * sizeof(int));
    int*    nstart = (int*)alloc((size_t)(kN + 1) * sizeof(int));
    int*    deg    = (int*)alloc((size_t)kN * sizeof(int));
    int*    degS   = (int*)alloc((size_t)kN * sizeof(int));
    int*    cursor = (int*)alloc((size_t)kN * sizeof(int));
    int*    order  = (int*)alloc((size_t)kN * sizeof(int));
    int*    rank   = (int*)alloc((size_t)kN * sizeof(int));
    int*    inc    = (int*)alloc((size_t)2 * kE * sizeof(int));
    int*    blkSum = (int*)alloc((size_t)kNB * sizeof(int));
    int*    blkOff = (int*)alloc((size_t)kNB * sizeof(int));
    int*    blkHist= (int*)alloc((size_t)kM * sizeof(int));
    int*    scanned= (int*)alloc((size_t)kM * sizeof(int));

    const int TB = 256;
    dim3 blk(TB);
    dim3 gE((kE + TB - 1) / TB);
    dim3 gN(kNB);
    dim3 g8N((8 * kN + TB - 1) / TB);

    // CSR build
    hipMemsetAsync(deg, 0, kN * sizeof(int), stream);
    count_kernel<<<gE, blk, 0, stream>>>(Cdist, deg);
    partial_sum_kernel<<<gN, blk, 0, stream>>>(deg, blkSum);
    scan_sums_kernel<<<dim3(1), blk, 0, stream>>>(blkSum, blkOff);
    scatter_scan_kernel<<<gN, blk, 0, stream>>>(deg, blkOff, start);
    hipMemcpyAsync(cursor, start, kN * sizeof(int), hipMemcpyDeviceToDevice, stream);
    fill_kernel<<<gE, blk, 0, stream>>>(Cdist, cursor, inc);

    // degree-sorted order, rank, sorted-degree scan -> nstart
    blk_hist_kernel<<<gN, blk, 0, stream>>>(deg, blkHist);
    sort_scan_kernel<<<dim3(1), dim3(1024), 0, stream>>>(blkHist, scanned);
    order_scatter_kernel<<<gN, blk, 0, stream>>>(deg, scanned, order);
    rank_kernel<<<gN, blk, 0, stream>>>(order, start, rank, degS);
    partial_sum_kernel<<<gN, blk, 0, stream>>>(degS, blkSum);
    scan_sums_kernel<<<dim3(1), blk, 0, stream>>>(blkSum, blkOff);
    scatter_scan_kernel<<<gN, blk, 0, stream>>>(degS, blkOff, nstart);

    // predict (coalesced) -> permute to sorted half planes -> slot arrays
    predict_kernel<<<gN, blk, 0, stream>>>(V, Vvel, Vw, Vcomp, Vmass, Vforce, Ptmp, WCtmp);
    permute_kernel<<<g8N, blk, 0, stream>>>(order, Ptmp, WCtmp, PA, WCs);
    slots_build_kernel<<<g8N, blk, 0, stream>>>(order, rank, start, nstart, inc,
                                                Cdist, Cinit, WCs, SSI, Aarr);
    hipMemsetAsync(L, 0, (size_t)2 * kHalfS * sizeof(float), stream);

    dim3 gS(kSweepBlocks);
    for (int it = 0; it < kIter; ++it) {
        float4* src = (it & 1) ? PB : PA;
        float4* dst = (it & 1) ? PA : PB;
        sweep_kernel<<<gS, blk, 0, stream>>>(src, dst, L, Aarr, SSI, nstart);
    }
    // 10 sweeps: final positions in PA. Un-sort + collision + velocity.
    float* outV   = (float*)d_out;
    float* outVel = outV + (size_t)kBN * 3;
    finalize_kernel<<<gN, blk, 0, stream>>>(PA, rank, V, outV, outVel);
}

// Round 11
// 298.469 us; speedup vs baseline: 2.9861x; 1.6430x over previous
//
#include <hip/hip_runtime.h>
#include <math.h>
#include <stdint.h>

namespace {
constexpr float kDT  = 0.01f;   // DT / SUBSTEP, SUBSTEP == 1
constexpr int   kIter = 10;
constexpr float kH   = -2.0f;
constexpr float kEps = 1e-5f;
constexpr int   kB = 8;
constexpr int   kN = 50000;
constexpr int   kE = 200000;
constexpr int   kBN = kB * kN;
constexpr int   kNB = (kN + 255) / 256;   // 196 blocks for per-vertex kernels
}

// ---------------- CSR build (once per launch) ----------------

__global__ void count_kernel(const int2* __restrict__ Cdist, int* __restrict__ counts) {
    int e = blockIdx.x * blockDim.x + threadIdx.x;
    if (e >= kE) return;
    int2 c = Cdist[e];
    atomicAdd(&counts[c.x], 1);
    atomicAdd(&counts[c.y], 1);
}

__global__ void partial_sum_kernel(const int* __restrict__ in, int* __restrict__ blkSum) {
    __shared__ int s[256];
    int i = blockIdx.x * 256 + threadIdx.x;
    s[threadIdx.x] = (i < kN) ? in[i] : 0;
    __syncthreads();
    for (int off = 128; off > 0; off >>= 1) {
        if (threadIdx.x < off) s[threadIdx.x] += s[threadIdx.x + off];
        __syncthreads();
    }
    if (threadIdx.x == 0) blkSum[blockIdx.x] = s[0];
}

__global__ void scan_sums_kernel(const int* __restrict__ blkSum, int* __restrict__ blkOff) {
    __shared__ int s[kNB];
    int tid = threadIdx.x;                 // 256 threads >= kNB
    if (tid < kNB) s[tid] = blkSum[tid];
    __syncthreads();
    if (tid == 0) {
        int acc = 0;
        for (int i = 0; i < kNB; ++i) { int v = s[i]; s[i] = acc; acc += v; }
    }
    __syncthreads();
    if (tid < kNB) blkOff[tid] = s[tid];
}

__global__ void scatter_scan_kernel(const int* __restrict__ in,
                                    const int* __restrict__ blkOff,
                                    int* __restrict__ out) {
    __shared__ int s[256];
    int tid = threadIdx.x;
    int i = blockIdx.x * 256 + tid;
    int c = (i < kN) ? in[i] : 0;
    s[tid] = c;
    __syncthreads();
    for (int off = 1; off < 256; off <<= 1) {      // inclusive Hillis-Steele
        int v = (tid >= off) ? s[tid - off] : 0;
        __syncthreads();
        s[tid] += v;
        __syncthreads();
    }
    int incl = s[tid];
    int excl = incl - c;
    if (i < kN) out[i] = blkOff[blockIdx.x] + excl;
    if (i == kN - 1) out[kN] = blkOff[blockIdx.x] + incl;   // == 2E
}

// inc id = 2*e + side. Atomic fill order only permutes slot order within a
// vertex; summation-order FP wiggle is far below tolerance (validated R1-R10).
__global__ void fill_kernel(const int2* __restrict__ Cdist, int* __restrict__ cursor,
                            int* __restrict__ inc) {
    int e = blockIdx.x * blockDim.x + threadIdx.x;
    if (e >= kE) return;
    int2 c = Cdist[e];
    int p0 = atomicAdd(&cursor[c.x], 1);
    inc[p0] = 2 * e;
    int p1 = atomicAdd(&cursor[c.y], 1);
    inc[p1] = 2 * e + 1;
}

// ---------------- predict + batch-minor re-layout ----------------

// P[v][b] = {x,y,z predicted, w};  Carr[v][b] = compliance
__global__ void predict_kernel(const float* __restrict__ V,
                               const float* __restrict__ Vvel,
                               const float* __restrict__ Vw,
                               const float* __restrict__ Vcomp,
                               const float* __restrict__ Vmass,
                               const float* __restrict__ Vforce,
                               float4* __restrict__ P,
                               float* __restrict__ Carr) {
    int v = blockIdx.x * blockDim.x + threadIdx.x;
    if (v >= kN) return;
#pragma unroll
    for (int b = 0; b < kB; ++b) {
        int idx = b * kN + v;
        int k = idx * 3;
        float m = Vmass[idx];
        float4 r;
        float vpx = Vvel[k + 0] + (kDT * Vforce[k + 0]) / m;   // (dt*F)/m, reference order
        float vpy = Vvel[k + 1] + (kDT * Vforce[k + 1]) / m;
        float vpz = Vvel[k + 2] + (kDT * Vforce[k + 2]) / m;
        r.x = V[k + 0] + kDT * vpx;
        r.y = V[k + 1] + kDT * vpy;
        r.z = V[k + 2] + kDT * vpz;
        r.w = Vw[idx];
        P[(size_t)v * 8 + b] = r;
        Carr[(size_t)v * 8 + b] = Vcomp[idx];
    }
}

// Per-slot: SS[k] = {other vertex, init_d bits}; Aarr[k][b] = (comp_i+comp_j)/2.
// A is symmetric -> both slot copies of an edge get bitwise-identical values,
// so the slot-duplicated L copies evolve bitwise in sync.
__global__ void slots_build_kernel(const int* __restrict__ inc,
                                   const int2* __restrict__ Cdist,
                                   const float* __restrict__ Cinit,
                                   const float* __restrict__ Carr,
                                   int2* __restrict__ SS,
                                   float* __restrict__ Aarr) {
    int k = blockIdx.x * blockDim.x + threadIdx.x;
    if (k >= 2 * kE) return;
    int ic = inc[k];
    int e = ic >> 1;
    int2 c = Cdist[e];
    int other = (ic & 1) ? c.x : c.y;
    SS[k] = make_int2(other, __float_as_int(Cinit[e]));
#pragma unroll
    for (int b = 0; b < kB; ++b) {
        float A = (Carr[(size_t)c.x * 8 + b] + Carr[(size_t)c.y * 8 + b]) * 0.5f;
        Aarr[(size_t)k * 8 + b] = A;
    }
}

// ---------------- fused Jacobi sweep ----------------
// Thread = (vertex v, batch b = lane&7): own/dst P and the neighbor gather are
// full 64B/128B lines shared by the 8 lanes; SS broadcasts; A/L are 32B runs.
// Each vertex recomputes its incident edges' corrections (Ld is bitwise
// identical from either endpoint: sign cancels in squares, adds commute), so
// no edge->vertex communication; per-slot L is owned by exactly one thread.
// rSA = 1/(S+A) with S = own.w + oth.w recomputed here (bitwise equal to a
// precomputed value; S==0 -> Ld=0 matches the reference's inf denominator).
// The k-loop is 2-wide software-pipelined: both gathers issue before compute.
// PHASE: 0 = first sweep (L assumed 0, not read), 1 = middle, 2 = last
// (plane-collision + velocity fused, writes d_out).
__device__ __forceinline__ void edge_op(const float4& own, const float4& oth,
                                        float A, float Lold, float initd,
                                        float* Lout,
                                        float& ax, float& ay, float& az) {
    float dx = own.x - oth.x;
    float dy = own.y - oth.y;
    float dz = own.z - oth.z;
    float D = sqrtf(dx * dx + dy * dy + dz * dz);
    float C = D - initd;
    float S = own.w + oth.w;
    float rSA = (S == 0.0f) ? 0.0f : 1.0f / (S + A);
    float Ld = (-C - A * Lold) * rSA;
    *Lout = Lold + Ld;
    float rD = 1.0f / D;
    ax += Ld * (dx * rD);
    ay += Ld * (dy * rD);
    az += Ld * (dz * rD);
}

template <int PHASE>
__global__ __launch_bounds__(256)
void sweep_kernel(const float4* __restrict__ Psrc,
                  float4* __restrict__ Pdst,
                  float* __restrict__ L,
                  const float* __restrict__ Aarr,
                  const int2* __restrict__ SS,
                  const int* __restrict__ start,
                  const float* __restrict__ V,
                  float* __restrict__ outV,
                  float* __restrict__ outVel) {
    int t = blockIdx.x * blockDim.x + threadIdx.x;
    if (t >= 8 * kN) return;
    int v = t >> 3;
    int b = t & 7;
    float4 own = Psrc[(size_t)v * 8 + b];
    int s0 = start[v], s1 = start[v + 1];
    float ax = 0.f, ay = 0.f, az = 0.f;

    int k = s0;
    for (; k + 1 < s1; k += 2) {
        int2 ss0 = SS[k];
        int2 ss1 = SS[k + 1];
        float4 o0 = Psrc[(size_t)ss0.x * 8 + b];   // two independent gathers
        float4 o1 = Psrc[(size_t)ss1.x * 8 + b];   // in flight together
        float A0 = Aarr[(size_t)k * 8 + b];
        float A1 = Aarr[(size_t)(k + 1) * 8 + b];
        float L0 = (PHASE == 0) ? 0.0f : L[(size_t)k * 8 + b];
        float L1 = (PHASE == 0) ? 0.0f : L[(size_t)(k + 1) * 8 + b];
        edge_op(own, o0, A0, L0, __int_as_float(ss0.y), &L[(size_t)k * 8 + b], ax, ay, az);
        edge_op(own, o1, A1, L1, __int_as_float(ss1.y), &L[(size_t)(k + 1) * 8 + b], ax, ay, az);
    }
    if (k < s1) {
        int2 ss = SS[k];
        float4 o = Psrc[(size_t)ss.x * 8 + b];
        float A = Aarr[(size_t)k * 8 + b];
        float Lold = (PHASE == 0) ? 0.0f : L[(size_t)k * 8 + b];
        edge_op(own, o, A, Lold, __int_as_float(ss.y), &L[(size_t)k * 8 + b], ax, ay, az);
    }

    float px = own.x + own.w * ax;
    float py = own.y + own.w * ay;
    float pz = own.z + own.w * az;
    if (PHASE != 2) {
        Pdst[(size_t)v * 8 + b] = make_float4(px, py, pz, own.w);
    } else {
        int k3 = (b * kN + v) * 3;
        float vx = V[k3], vy = V[k3 + 1], vz0 = V[k3 + 2];

        bool col = (pz < kH) && (vz0 > kH);
        float h_prev = vz0 - kH;
        float h_after = kH - pz;
        float denom = col ? (h_prev + h_after) : 1.0f;
        float tt = h_prev / denom;

        float x  = col ? (vx + tt * (px - vx)) : px;
        float y  = col ? (vy + tt * (py - vy)) : py;
        float z1 = col ? (kH + kEps) : pz;

        bool vio = (z1 < kH) && (vz0 < kH);
        float z2 = vio ? (kH + kEps) : z1;

        float velx = (x  - vx ) / kDT;
        float vely = (y  - vy ) / kDT;
        float velz = (z2 - vz0) / kDT;
        velz = col ? -velz : velz;
        velz = vio ? 0.0f : velz;

        outV[k3] = x;  outV[k3 + 1] = y;  outV[k3 + 2] = z2;
        outVel[k3] = velx; outVel[k3 + 1] = vely; outVel[k3 + 2] = velz;
    }
}

// ---------------- launch ----------------

extern "C" void kernel_launch(void* const* d_in, const int* in_sizes, int n_in,
                              void* d_out, int out_size, void* d_ws, size_t ws_size,
                              hipStream_t stream) {
    const float* V      = (const float*)d_in[0];
    const float* Vvel   = (const float*)d_in[1];
    const float* Vw     = (const float*)d_in[2];
    const float* Vcomp  = (const float*)d_in[3];
    const float* Vmass  = (const float*)d_in[4];
    const float* Vforce = (const float*)d_in[5];
    const float* Cinit  = (const float*)d_in[6];
    const int2*  Cdist  = (const int2*)d_in[7];

    char* p = (char*)d_ws;
    auto alloc = [&](size_t bytes) -> void* {
        p = (char*)(((uintptr_t)p + 255) & ~(uintptr_t)255);
        void* r = (void*)p;
        p += bytes;
        return r;
    };

    float4* PA     = (float4*)alloc((size_t)kN * 8 * sizeof(float4));       // 6.4 MB
    float4* PB     = (float4*)alloc((size_t)kN * 8 * sizeof(float4));       // 6.4 MB
    float*  L      = (float*)alloc((size_t)2 * kE * 8 * sizeof(float));     // 12.8 MB
    float*  Aarr   = (float*)alloc((size_t)2 * kE * 8 * sizeof(float));     // 12.8 MB
    int2*   SS     = (int2*)alloc((size_t)2 * kE * sizeof(int2));           // 3.2 MB
    float*  Carr   = (float*)alloc((size_t)kN * 8 * sizeof(float));         // 1.6 MB
    int*    start  = (int*)alloc((size_t)(kN + 1) * sizeof(int));
    int*    cursor = (int*)alloc((size_t)kN * sizeof(int));
    int*    inc    = (int*)alloc((size_t)2 * kE * sizeof(int));
    int*    blkSum = (int*)alloc((size_t)kNB * sizeof(int));
    int*    blkOff = (int*)alloc((size_t)kNB * sizeof(int));

    const int TB = 256;
    dim3 blk(TB);
    dim3 gE((kE + TB - 1) / TB);
    dim3 g2E((2 * kE + TB - 1) / TB);
    dim3 gN(kNB);
    dim3 g8N((8 * kN + TB - 1) / TB);

    // CSR build (cursor doubles as counts)
    hipMemsetAsync(cursor, 0, kN * sizeof(int), stream);
    count_kernel<<<gE, blk, 0, stream>>>(Cdist, cursor);
    partial_sum_kernel<<<gN, blk, 0, stream>>>(cursor, blkSum);
    scan_sums_kernel<<<dim3(1), blk, 0, stream>>>(blkSum, blkOff);
    scatter_scan_kernel<<<gN, blk, 0, stream>>>(cursor, blkOff, start);
    hipMemcpyAsync(cursor, start, kN * sizeof(int), hipMemcpyDeviceToDevice, stream);
    fill_kernel<<<gE, blk, 0, stream>>>(Cdist, cursor, inc);

    // predict + batch-minor layout, then per-slot invariants (no L memset:
    // sweep PHASE 0 writes every (slot,b) without reading)
    predict_kernel<<<gN, blk, 0, stream>>>(V, Vvel, Vw, Vcomp, Vmass, Vforce, PA, Carr);
    slots_build_kernel<<<g2E, blk, 0, stream>>>(inc, Cdist, Cinit, Carr, SS, Aarr);

    float* outV   = (float*)d_out;
    float* outVel = outV + (size_t)kBN * 3;

    for (int it = 0; it < kIter; ++it) {
        float4* src = (it & 1) ? PB : PA;
        float4* dst = (it & 1) ? PA : PB;
        if (it == 0) {
            sweep_kernel<0><<<g8N, blk, 0, stream>>>(src, dst, L, Aarr, SS, start,
                                                     V, outV, outVel);
        } else if (it < kIter - 1) {
            sweep_kernel<1><<<g8N, blk, 0, stream>>>(src, dst, L, Aarr, SS, start,
                                                     V, outV, outVel);
        } else {
            sweep_kernel<2><<<g8N, blk, 0, stream>>>(src, dst, L, Aarr, SS, start,
                                                     V, outV, outVel);
        }
    }
}